// Round 1
// baseline (152.001 us; speedup 1.0000x reference)
//
#include <hip/hip_runtime.h>

#define TH   32                 // output rows per block
#define HALO 3                  // window radius
#define NR   (TH + 2*HALO)      // 38 staged rows
#define W    256
#define H    256
#define LDSW (W + 2*HALO + 2)   // 264: 3 left pad, 3 right pad, 2 unused

__global__ __launch_bounds__(256, 4)
void rg_kernel(const float* __restrict__ x, float* __restrict__ out) {
    __shared__ float d_lds[NR][LDSW];

    const int col   = threadIdx.x;          // 0..255, one thread per column
    const int rt    = blockIdx.x & 7;       // row tile within plane (256/32 = 8)
    const int plane = blockIdx.x >> 3;      // b*64 + c, 0..511
    const int row0  = rt * TH;

    const float* xp = x + (size_t)plane * (W * H);

    // Phase 1: stage d = 0.5*exp(x^2 - x) with zero halo (rows and cols)
    for (int lr = 0; lr < NR; ++lr) {
        int row = row0 - HALO + lr;
        float d = 0.0f;
        if ((unsigned)row < (unsigned)H) {
            float v = xp[row * W + col];
            d = 0.5f * __expf(__fmaf_rn(v, v, -v));
        }
        d_lds[lr][col + HALO] = d;
        if (col < HALO) {                    // zero the horizontal pads
            d_lds[lr][col] = 0.0f;
            d_lds[lr][W + HALO + col] = 0.0f;
        }
    }
    __syncthreads();

    // horizontal valid-count for this column
    int cl = col - HALO; cl = cl < 0 ? 0 : cl;
    int cr = col + HALO; cr = cr > W - 1 ? W - 1 : cr;
    const float cnt_h = (float)(cr - cl + 1);

    // hsum(lr): 7-wide horizontal sum centered at `col` (pads are zero)
    #define HSUM(lr_) ({ const float* p_ = &d_lds[(lr_)][col];                 \
                         ((p_[0]+p_[1]) + (p_[2]+p_[3])) + ((p_[4]+p_[5]) + p_[6]); })

    float h0 = HSUM(0), h1 = HSUM(1), h2 = HSUM(2),
          h3 = HSUM(3), h4 = HSUM(4), h5 = HSUM(5);

    const int b = plane >> 6, c = plane & 63;
    float* outx = out + ((size_t)b * 128 + c) * (size_t)(W * H);
    float* outr = outx + (size_t)64 * (W * H);

    #pragma unroll 4
    for (int i = 0; i < TH; ++i) {
        float h6 = HSUM(i + 6);
        float vs = ((h0 + h1) + (h2 + h3)) + ((h4 + h5) + h6);

        int row = row0 + i;
        int rl = row - HALO; rl = rl < 0 ? 0 : rl;
        int rr = row + HALO; rr = rr > H - 1 ? H - 1 : rr;
        float cnt = cnt_h * (float)(rr - rl + 1);

        float v = xp[row * W + col];          // L1/L2-hot re-read
        size_t o = (size_t)row * W + col;
        outx[o] = v;                          // concat first half: copy of x
        outr[o] = vs * __builtin_amdgcn_rcpf(cnt) * __expf(v);

        h0 = h1; h1 = h2; h2 = h3; h3 = h4; h4 = h5; h5 = h6;
    }
    #undef HSUM
}

extern "C" void kernel_launch(void* const* d_in, const int* in_sizes, int n_in,
                              void* d_out, int out_size, void* d_ws, size_t ws_size,
                              hipStream_t stream) {
    const float* x = (const float*)d_in[0];
    float* out = (float*)d_out;
    int n = in_sizes[0];
    int planes = n / (W * H);                 // 512
    int grid = planes * (H / TH);             // 4096
    rg_kernel<<<dim3(grid), dim3(256), 0, stream>>>(x, out);
}

// Round 2
// 92.354 us; speedup vs baseline: 1.6458x; 1.6458x over previous
//
#include <hip/hip_runtime.h>

#define TH   32                 // output rows per block
#define HALO 3                  // window radius
#define NR   (TH + 2*HALO)      // 38 staged hsum rows
#define W    256
#define H    256

__global__ __launch_bounds__(256, 4)
void rg_kernel(const float* __restrict__ x, float* __restrict__ out) {
    __shared__ float hs[NR][W];             // horizontal 7-sums, 38 KB

    const int tx = threadIdx.x & 63;        // col-group: cols 4tx..4tx+3 (wave = one row)
    const int ty = threadIdx.x >> 6;        // 0..3 (thread-row)
    const int c0 = tx << 2;

    const int rt    = blockIdx.x & 7;       // row tile within plane
    const int plane = blockIdx.x >> 3;      // b*64 + c
    const int row0  = rt * TH;

    const float* xp = x + (size_t)plane * (W * H);

    // Phase 1: stage horizontal 7-sums of d = 0.5*exp(x^2-x) into LDS.
    // Wave-uniform lr (all lanes share ty,it) -> shuffles are safe inside branches.
    #pragma unroll
    for (int it = 0; it < 10; ++it) {
        const int lr = ty + (it << 2);
        if (lr < NR) {
            const int row = row0 - HALO + lr;
            float4 d = make_float4(0.f, 0.f, 0.f, 0.f);
            if ((unsigned)row < (unsigned)H) {
                float4 v = *(const float4*)(xp + row * W + c0);
                d.x = 0.5f * __expf(__fmaf_rn(v.x, v.x, -v.x));
                d.y = 0.5f * __expf(__fmaf_rn(v.y, v.y, -v.y));
                d.z = 0.5f * __expf(__fmaf_rn(v.z, v.z, -v.z));
                d.w = 0.5f * __expf(__fmaf_rn(v.w, v.w, -v.w));
            }
            // cols c0-3..c0-1 live in lane tx-1 (.y,.z,.w); c0+4..c0+6 in lane tx+1 (.x,.y,.z)
            float dmy = __shfl_up(d.y, 1);
            float dmz = __shfl_up(d.z, 1);
            float dmw = __shfl_up(d.w, 1);
            float dpx = __shfl_down(d.x, 1);
            float dpy = __shfl_down(d.y, 1);
            float dpz = __shfl_down(d.z, 1);
            if (tx == 0)  { dmy = 0.f; dmz = 0.f; dmw = 0.f; }
            if (tx == 63) { dpx = 0.f; dpy = 0.f; dpz = 0.f; }
            const float s = (d.x + d.y) + (d.z + d.w);
            float4 h;
            h.x = ((dmy + dmz) + dmw) + s;
            h.y = (dmz + dmw) + (s + dpx);
            h.z = dmw + (s + (dpx + dpy));
            h.w = s + ((dpx + dpy) + dpz);
            *(float4*)&hs[lr][c0] = h;
        }
    }
    __syncthreads();

    // per-column reciprocal window counts (hoisted)
    float4 rch;
    rch.x = __builtin_amdgcn_rcpf((float)(min(c0 + 3, W - 1) - max(c0 - 3, 0) + 1));
    rch.y = __builtin_amdgcn_rcpf((float)(min(c0 + 4, W - 1) - max(c0 - 2, 0) + 1));
    rch.z = __builtin_amdgcn_rcpf((float)(min(c0 + 5, W - 1) - max(c0 - 1, 0) + 1));
    rch.w = __builtin_amdgcn_rcpf((float)(min(c0 + 6, W - 1) - max(c0 + 0, 0) + 1));

    const int i0 = ty << 3;                 // this thread's 8 output rows: row0+i0 .. +7
    float4 h0 = *(float4*)&hs[i0 + 0][c0];
    float4 h1 = *(float4*)&hs[i0 + 1][c0];
    float4 h2 = *(float4*)&hs[i0 + 2][c0];
    float4 h3 = *(float4*)&hs[i0 + 3][c0];
    float4 h4 = *(float4*)&hs[i0 + 4][c0];
    float4 h5 = *(float4*)&hs[i0 + 5][c0];

    const int b = plane >> 6, cch = plane & 63;
    float* outx = out + ((size_t)(b * 128 + cch)) * (size_t)(W * H);
    float* outr = outx + (size_t)64 * (W * H);

    #pragma unroll
    for (int j = 0; j < 8; ++j) {
        float4 h6 = *(float4*)&hs[i0 + j + 6][c0];
        float4 vs;
        vs.x = ((h0.x + h1.x) + (h2.x + h3.x)) + ((h4.x + h5.x) + h6.x);
        vs.y = ((h0.y + h1.y) + (h2.y + h3.y)) + ((h4.y + h5.y) + h6.y);
        vs.z = ((h0.z + h1.z) + (h2.z + h3.z)) + ((h4.z + h5.z) + h6.z);
        vs.w = ((h0.w + h1.w) + (h2.w + h3.w)) + ((h4.w + h5.w) + h6.w);

        const int row = row0 + i0 + j;
        const float cv  = (float)(min(row + 3, H - 1) - max(row - 3, 0) + 1);
        const float rcv = __builtin_amdgcn_rcpf(cv);

        float4 xv = *(const float4*)(xp + row * W + c0);   // L1/L2-hot re-read
        const size_t o = (size_t)row * W + c0;
        *(float4*)(outx + o) = xv;                         // concat first half
        float4 r;
        r.x = vs.x * (rch.x * rcv) * __expf(xv.x);
        r.y = vs.y * (rch.y * rcv) * __expf(xv.y);
        r.z = vs.z * (rch.z * rcv) * __expf(xv.z);
        r.w = vs.w * (rch.w * rcv) * __expf(xv.w);
        *(float4*)(outr + o) = r;

        h0 = h1; h1 = h2; h2 = h3; h3 = h4; h4 = h5; h5 = h6;
    }
}

extern "C" void kernel_launch(void* const* d_in, const int* in_sizes, int n_in,
                              void* d_out, int out_size, void* d_ws, size_t ws_size,
                              hipStream_t stream) {
    const float* x = (const float*)d_in[0];
    float* out = (float*)d_out;
    int n = in_sizes[0];
    int planes = n / (W * H);               // 512
    int grid = planes * (H / TH);           // 4096
    rg_kernel<<<dim3(grid), dim3(256), 0, stream>>>(x, out);
}

// Round 3
// 79.116 us; speedup vs baseline: 1.9212x; 1.1673x over previous
//
#include <hip/hip_runtime.h>

#define TH   32                 // output rows per block
#define HALO 3                  // window radius
#define NR   (TH + 2*HALO)      // 38 staged hsum rows
#define W    256
#define H    256

__global__ __launch_bounds__(256, 4)
void rg_kernel(const float* __restrict__ x, float* __restrict__ out) {
    __shared__ float hs[NR][W];             // horizontal 7-sums, 38 KB

    const int tx = threadIdx.x & 63;        // col-group: cols 4tx..4tx+3 (wave = one row-set)
    const int ty = threadIdx.x >> 6;        // 0..3
    const int c0 = tx << 2;

    const int rt    = blockIdx.x & 7;       // row tile within plane
    const int plane = blockIdx.x >> 3;      // b*64 + c
    const int row0  = rt * TH;
    const int i0    = ty << 3;              // this thread's 8 output rows: row0+i0 ..+7

    const float* xp = x + (size_t)plane * (W * H);
    const int b = plane >> 6, cch = plane & 63;
    float* outx = out + ((size_t)(b * 128 + cch)) * (size_t)(W * H);
    float* outr = outx + (size_t)64 * (W * H);

    // ---- Phase 1a: issue ALL global loads in one burst ----
    float4 xv[8];
    const float* rp = xp + (row0 + i0) * W + c0;   // always in-plane
    #pragma unroll
    for (int j = 0; j < 8; ++j)
        xv[j] = *(const float4*)(rp + j * W);

    // halo rows (wave-uniform conditions): ty=0..2 -> top row row0-3+ty (lr=ty)
    //                                      ty=1..3 -> bottom row row0+31+ty (lr=34+ty)
    float4 hvt = make_float4(0.f, 0.f, 0.f, 0.f), hvb = hvt;
    const int rowt = row0 - 3 + ty;
    const int rowb = row0 + 31 + ty;
    if (ty <= 2 && rowt >= 0) hvt = *(const float4*)(xp + rowt * W + c0);
    if (ty >= 1 && rowb < H)  hvb = *(const float4*)(xp + rowb * W + c0);

    // ---- Phase 1b: d = 0.5*exp(x^2-x), horizontal 7-sum via shuffles, LDS store ----
    auto stage = [&](float4 v, int lr) {    // must be called wave-uniformly
        float4 d;
        d.x = 0.5f * __expf(__fmaf_rn(v.x, v.x, -v.x));
        d.y = 0.5f * __expf(__fmaf_rn(v.y, v.y, -v.y));
        d.z = 0.5f * __expf(__fmaf_rn(v.z, v.z, -v.z));
        d.w = 0.5f * __expf(__fmaf_rn(v.w, v.w, -v.w));
        float dmy = __shfl_up(d.y, 1);
        float dmz = __shfl_up(d.z, 1);
        float dmw = __shfl_up(d.w, 1);
        float dpx = __shfl_down(d.x, 1);
        float dpy = __shfl_down(d.y, 1);
        float dpz = __shfl_down(d.z, 1);
        if (tx == 0)  { dmy = 0.f; dmz = 0.f; dmw = 0.f; }
        if (tx == 63) { dpx = 0.f; dpy = 0.f; dpz = 0.f; }
        const float s = (d.x + d.y) + (d.z + d.w);
        float4 h;
        h.x = ((dmy + dmz) + dmw) + s;
        h.y = (dmz + dmw) + (s + dpx);
        h.z = dmw + (s + (dpx + dpy));
        h.w = s + ((dpx + dpy) + dpz);
        *(float4*)&hs[lr][c0] = h;
    };

    #pragma unroll
    for (int j = 0; j < 8; ++j) {
        stage(xv[j], i0 + 3 + j);
        // concat first half: copy of x, straight from registers (overlaps exp work)
        *(float4*)(outx + (size_t)(row0 + i0 + j) * W + c0) = xv[j];
    }
    if (ty <= 2) stage(hvt, ty);            // zero rows if out-of-plane
    if (ty >= 1) stage(hvb, 34 + ty);
    __syncthreads();

    // ---- Phase 2: vertical 7-window over hsums, no global loads ----
    float4 rch;
    rch.x = __builtin_amdgcn_rcpf((float)(min(c0 + 3, W - 1) - max(c0 - 3, 0) + 1));
    rch.y = __builtin_amdgcn_rcpf((float)(min(c0 + 4, W - 1) - max(c0 - 2, 0) + 1));
    rch.z = __builtin_amdgcn_rcpf((float)(min(c0 + 5, W - 1) - max(c0 - 1, 0) + 1));
    rch.w = __builtin_amdgcn_rcpf((float)(min(c0 + 6, W - 1) - max(c0 + 0, 0) + 1));

    float4 h0 = *(float4*)&hs[i0 + 0][c0];
    float4 h1 = *(float4*)&hs[i0 + 1][c0];
    float4 h2 = *(float4*)&hs[i0 + 2][c0];
    float4 h3 = *(float4*)&hs[i0 + 3][c0];
    float4 h4 = *(float4*)&hs[i0 + 4][c0];
    float4 h5 = *(float4*)&hs[i0 + 5][c0];

    #pragma unroll
    for (int j = 0; j < 8; ++j) {
        float4 h6 = *(float4*)&hs[i0 + j + 6][c0];
        float4 vs;
        vs.x = ((h0.x + h1.x) + (h2.x + h3.x)) + ((h4.x + h5.x) + h6.x);
        vs.y = ((h0.y + h1.y) + (h2.y + h3.y)) + ((h4.y + h5.y) + h6.y);
        vs.z = ((h0.z + h1.z) + (h2.z + h3.z)) + ((h4.z + h5.z) + h6.z);
        vs.w = ((h0.w + h1.w) + (h2.w + h3.w)) + ((h4.w + h5.w) + h6.w);

        const int row = row0 + i0 + j;
        const float rcv = __builtin_amdgcn_rcpf(
            (float)(min(row + 3, H - 1) - max(row - 3, 0) + 1));

        float4 r;
        r.x = vs.x * (rch.x * rcv) * __expf(xv[j].x);
        r.y = vs.y * (rch.y * rcv) * __expf(xv[j].y);
        r.z = vs.z * (rch.z * rcv) * __expf(xv[j].z);
        r.w = vs.w * (rch.w * rcv) * __expf(xv[j].w);
        *(float4*)(outr + (size_t)row * W + c0) = r;

        h0 = h1; h1 = h2; h2 = h3; h3 = h4; h4 = h5; h5 = h6;
    }
}

extern "C" void kernel_launch(void* const* d_in, const int* in_sizes, int n_in,
                              void* d_out, int out_size, void* d_ws, size_t ws_size,
                              hipStream_t stream) {
    const float* x = (const float*)d_in[0];
    float* out = (float*)d_out;
    int n = in_sizes[0];
    int planes = n / (W * H);               // 512
    int grid = planes * (H / TH);           // 4096
    rg_kernel<<<dim3(grid), dim3(256), 0, stream>>>(x, out);
}